// Round 3
// baseline (86.304 us; speedup 1.0000x reference)
//
#include <hip/hip_runtime.h>

// HilbertSimulator — closed-form reduction.
//
// RY(x_i) then RY(w_i) on |0000> gives a product state with theta_i=x_i+w_i.
// CNOT ring is GF(2)-linear; Z-expectation of XOR-of-bits factorizes over a
// product distribution into products of d_i = cos(2*theta_i):
//   out = ( d1*d2*d3, d0*d1, d0*d1*d2, d0*d1*d2*d3 )
//
// Pure streaming kernel: 16 B in + 16 B out per batch element (64 MiB total).
// Memory-bound; compute (4x v_cos_f32/elem) is <1 us chip-wide.
// ELEMS_PER_THREAD=4 -> 2048 blocks x 256 thr = 8192 waves = one full
// residency generation on 256 CUs. Nontemporal: streaming data, no reuse.
//
// NOTE: __builtin_nontemporal_* requires a clang vector type, not HIP's
// float4 struct — hence the ext_vector_type typedef.

typedef float vfloat4 __attribute__((ext_vector_type(4)));

#define ELEMS_PER_THREAD 4

__global__ __launch_bounds__(256) void HilbertSimulator_12275016532163_kernel(
    const vfloat4* __restrict__ x,   // (BATCH, 4) as vector-of-4
    const float*   __restrict__ w,   // (1, 4)
    vfloat4*       __restrict__ out, // (BATCH, 4) as vector-of-4
    int batch)
{
    const float w0 = w[0], w1 = w[1], w2 = w[2], w3 = w[3];

    const int stride = gridDim.x * blockDim.x;
    int b = blockIdx.x * blockDim.x + threadIdx.x;

#pragma unroll
    for (int it = 0; it < ELEMS_PER_THREAD; ++it, b += stride) {
        if (b < batch) {
            const vfloat4 xv = __builtin_nontemporal_load(&x[b]);  // 16 B/lane

            const float d0 = __cosf(2.0f * (xv.x + w0));
            const float d1 = __cosf(2.0f * (xv.y + w1));
            const float d2 = __cosf(2.0f * (xv.z + w2));
            const float d3 = __cosf(2.0f * (xv.w + w3));

            vfloat4 o;
            o.y = d0 * d1;        // <Z1>
            o.x = d1 * d2 * d3;   // <Z0>
            o.z = o.y * d2;       // <Z2>
            o.w = o.z * d3;       // <Z3>

            __builtin_nontemporal_store(o, &out[b]);  // 16 B/lane
        }
    }
}

extern "C" void kernel_launch(void* const* d_in, const int* in_sizes, int n_in,
                              void* d_out, int out_size, void* d_ws, size_t ws_size,
                              hipStream_t stream) {
    const vfloat4* x = (const vfloat4*)d_in[0];
    const float*   w = (const float*)d_in[1];
    vfloat4* out = (vfloat4*)d_out;

    const int batch = in_sizes[0] / 4;   // x is (BATCH, 4) fp32
    const int block = 256;
    const int grid  = (batch + block * ELEMS_PER_THREAD - 1) / (block * ELEMS_PER_THREAD);

    HilbertSimulator_12275016532163_kernel<<<grid, block, 0, stream>>>(x, w, out, batch);
}

// Round 4
// 81.411 us; speedup vs baseline: 1.0601x; 1.0601x over previous
//
#include <hip/hip_runtime.h>

// HilbertSimulator — closed-form reduction.
//
// Reference circuit: RY(x_i) then RY(w_i) per qubit on |0000> (RY compose:
// angle theta_i = x_i + w_i -> product state), then 4 CNOTs (a GF(2)-linear
// permutation), then probs @ Z. Z-expectation of an XOR-of-bits factorizes
// over a product distribution into a product of cos(2*theta_i):
//   d_i = cos(2*(x_i + w_i))
//   out = ( d1*d2*d3, d0*d1, d0*d1*d2, d0*d1*d2*d3 )
//
// Streaming kernel: 16 B in + 16 B out per batch element (64 MiB total) at
// HBM roofline ~11 us. Timed-loop residual (~70 us) is harness reset fills
// (256 MiB ws + 32 MiB out poison + input restore), visible in rocprof at
// 75-80% HBM peak — not addressable from kernel code.
//
// R3 post-mortem: nontemporal hints + x4 grid-stride regressed (or was run
// variance); plain 1-elem/thread float4 measured best (80.9 us) — reverted.

__global__ __launch_bounds__(256) void HilbertSimulator_12275016532163_kernel(
    const float4* __restrict__ x,   // (BATCH, 4) as float4
    const float*  __restrict__ w,   // (1, 4)
    float4*       __restrict__ out, // (BATCH, 4) as float4
    int batch)
{
    const int b = blockIdx.x * blockDim.x + threadIdx.x;
    if (b >= batch) return;

    // Uniform weights -> scalar loads (broadcast via constant cache).
    const float w0 = w[0], w1 = w[1], w2 = w[2], w3 = w[3];

    const float4 xv = x[b];   // coalesced 16 B/lane

    const float d0 = __cosf(2.0f * (xv.x + w0));
    const float d1 = __cosf(2.0f * (xv.y + w1));
    const float d2 = __cosf(2.0f * (xv.z + w2));
    const float d3 = __cosf(2.0f * (xv.w + w3));

    float4 o;
    o.y = d0 * d1;           // <Z1> = d0*d1
    o.x = d1 * d2 * d3;      // <Z0> = d1*d2*d3
    o.z = o.y * d2;          // <Z2> = d0*d1*d2
    o.w = o.z * d3;          // <Z3> = d0*d1*d2*d3

    out[b] = o;              // coalesced 16 B/lane
}

extern "C" void kernel_launch(void* const* d_in, const int* in_sizes, int n_in,
                              void* d_out, int out_size, void* d_ws, size_t ws_size,
                              hipStream_t stream) {
    const float4* x = (const float4*)d_in[0];
    const float*  w = (const float*)d_in[1];
    float4* out = (float4*)d_out;

    const int batch = in_sizes[0] / 4;   // x is (BATCH, 4) fp32
    const int block = 256;
    const int grid  = (batch + block - 1) / block;

    HilbertSimulator_12275016532163_kernel<<<grid, block, 0, stream>>>(x, w, out, batch);
}